// Round 5
// baseline (890.599 us; speedup 1.0000x reference)
//
#include <hip/hip_runtime.h>
#include <stdint.h>

#define LVL 24
#define NN  8192
#define DIN 256
#define DD  128
#define BM  32       // nodes per block; block covers ALL 128 d (8 waves, one 16-d slice each)
#define CSW 132      // cs row stride (floats): 16B-aligned; <=4-way write, 2-way read conflicts

typedef __attribute__((ext_vector_type(8))) short bf16x8;
typedef __attribute__((ext_vector_type(4))) float f32x4;

__device__ __forceinline__ float b2f(unsigned short u) {
    union { unsigned int i; float f; } v; v.i = ((unsigned int)u) << 16; return v.f;
}
__device__ __forceinline__ unsigned short f2b(float f) {
    union { float f; unsigned int i; } v; v.f = f;
    unsigned int x = v.i;
    return (unsigned short)((x + 0x7fffu + ((x >> 16) & 1u)) >> 16);  // RNE
}
__device__ __forceinline__ float sig_(float x) { return 1.0f / (1.0f + __expf(-x)); }
// fast tanh: (e^{2x}-1)/(e^{2x}+1); exact at +-inf saturation, ~1e-6 abs err near 0
__device__ __forceinline__ float tanh_(float x) {
    float e = __expf(2.0f * x);
    return (e - 1.0f) / (e + 1.0f);
}

__device__ __forceinline__ float ldf(const void* p, size_t i, int isf) {
    return isf ? ((const float*)p)[i] : b2f(((const unsigned short*)p)[i]);
}

// ---------------- dtype detector (unchanged) ----------------
__global__ void detect_kernel(const unsigned short* __restrict__ t, int* __restrict__ flag) {
    __shared__ int cnt;
    if (threadIdx.x == 0) cnt = 0;
    __syncthreads();
    int bad = 0;
    #pragma unroll
    for (int r = 0; r < 4; ++r) {
        unsigned short u = t[(threadIdx.x * 4 + r) * 2];
        int e = (u >> 7) & 255;
        bad += (e >= 136 || (e >= 1 && e <= 90)) ? 1 : 0;
    }
    atomicAdd(&cnt, bad);
    __syncthreads();
    if (threadIdx.x == 0) *flag = (cnt > 16) ? 1 : 0;
}

// ---------------- weight conversion into FRAGMENT-MAJOR packed layout (unchanged) ----------------
// Logical rows: [0,512)=W_w(f,i,u,o); [512,640)=U_f1; [640,768)=U_f2; [768,1152)=U_iuo.
// Packed element index: ((g*8+dt)*8 + kk)*512 + (q*16+m)*8 + j
//   where row = g*128 + dt*16 + m, col = kk*32 + q*8 + j.
// A wave's B-fragment load (g,dt,kk) is 64 lanes x 16B fully contiguous (1 KB).
__global__ __launch_bounds__(256)
void convert_kernel(const void* Ww, const void* Wb, const void* Uf1, const void* Uf2,
                    const void* Uiuo, const void* hini, const void* cini,
                    unsigned short* __restrict__ wpack, float* __restrict__ bias,
                    unsigned short* __restrict__ hinit_b, float* __restrict__ cinit_f,
                    const int* __restrict__ flag) {
    const int isf = *flag;
    const int bid = blockIdx.x;
    const int t = threadIdx.x;
    if (bid < 1152) {
        const int row = bid, col = t;
        float v;
        if (row < 512)       v = ldf(Ww,   (size_t)row * DIN + col, isf);
        else if (row < 640)  v = ldf(Uf1,  (size_t)(row - 512) * DIN + col, isf);
        else if (row < 768)  v = ldf(Uf2,  (size_t)(row - 640) * DIN + col, isf);
        else                 v = ldf(Uiuo, (size_t)(row - 768) * DIN + col, isf);
        const int g  = row >> 7;
        const int wr = row & 127;
        const int dt = wr >> 4;
        const int mm = wr & 15;
        const int kk = col >> 5;
        const int q  = (col >> 3) & 3;
        const int j  = col & 7;
        const size_t pos = (size_t)((g * 8 + dt) * 8 + kk) * 512 + (q * 16 + mm) * 8 + j;
        wpack[pos] = f2b(v);
    } else if (bid == 1152) {
        bias[t] = ldf(Wb, t, isf);
    } else if (bid == 1153) {
        bias[256 + t] = ldf(Wb, 256 + t, isf);
    } else {
        if (t < 128) hinit_b[t] = f2b(ldf(hini, t, isf));
        else if (t < 256) cinit_f[t - 128] = ldf(cini, t - 128, isf);
    }
}

// ---------------- one tree level: BM=32 nodes x ALL 128 d, 512 threads (8 waves) ----------------
// Traffic per block: x 32KB(fp32) read ONCE; h gather 16KB; c gather 32KB; weights 576KB from L2.
// Grid 256 blocks -> every traffic stream at its per-run minimum:
//   x 192MB/run, h 4MB/level, c 8MB/level, weights 18KB/node.
// x/h LDS fragment layout: element (kk,q,r,j) at ushort index kk*1024 + q*256 + r*8 + j
//   == row r (0..31), col kk*32+q*8+j. MFMA reads are 16-lane contiguous 256B -> conflict-free.
__global__ __launch_bounds__(512, 4)   // 4 waves/EU -> 2 blocks/CU cap, VGPR <= 128
void level_kernel(const void* __restrict__ xbase, int level,
                  const int* __restrict__ idx,              // [NN,2] this level
                  const unsigned short* __restrict__ hprev, // [NN,DD] bf16
                  const float* __restrict__ cprev,          // [NN,DD] fp32 (out slab l-1)
                  unsigned short* __restrict__ hnew,        // [NN,DD] bf16
                  float* __restrict__ outh,                 // [NN,DD] fp32
                  float* __restrict__ outc,                 // [NN,DD] fp32 (c state for l+1)
                  const unsigned short* __restrict__ wpack,
                  const float* __restrict__ bias,
                  const unsigned short* __restrict__ hinit_b,
                  const float* __restrict__ cinit_f,
                  const int* __restrict__ flag,
                  int first) {
    __shared__ unsigned short xs[8192];   // 16 KB  [32 x 256] bf16 fragment-linear
    __shared__ unsigned short hs[8192];   // 16 KB  [32 x 256] child-h concat
    __shared__ float cs[64 * CSW];        // 33.8 KB [ (s*32+r) x 128 ] child-c

    const int tid = threadIdx.x;
    const int isf = *flag;
    const int bm  = blockIdx.x;

    // ---- gather roles (issue idx load first so gather latency overlaps x staging) ----
    const int gr = tid & 31;              // node row
    const int gs = (tid >> 5) & 1;        // child 0/1
    const int p2 = tid >> 6;              // 0..7 chunk group
    const int ai = idx[(bm * BM + gr) * 2 + gs];
    const int use_init = (first || ai < 0);

    // ---- stage x tile: r = tid&31, octets u0 and u0+16 ----
    {
        const int r  = tid & 31;
        const int u0 = tid >> 5;          // 0..15
        #pragma unroll
        for (int du = 0; du < 2; ++du) {
            const int u = u0 + du * 16;   // octet of the 256-wide row
            const int kk = u >> 2, qq = u & 3;
            const size_t re = (size_t)level * NN * DIN + (size_t)(bm * BM + r) * DIN + u * 8;
            union { unsigned short us[8]; uint4 v; } t;
            if (isf) {
                const float4* xr = (const float4*)((const float*)xbase + re);
                float4 v0 = xr[0], v1 = xr[1];
                t.us[0] = f2b(v0.x); t.us[1] = f2b(v0.y); t.us[2] = f2b(v0.z); t.us[3] = f2b(v0.w);
                t.us[4] = f2b(v1.x); t.us[5] = f2b(v1.y); t.us[6] = f2b(v1.z); t.us[7] = f2b(v1.w);
            } else {
                t.v = *(const uint4*)((const unsigned short*)xbase + re);
            }
            *(uint4*)&xs[kk * 1024 + qq * 256 + r * 8] = t.v;
        }
    }

    // ---- gather children h (bf16, 2x16B/thread) and c (fp32, 4x16B/thread) ----
    {
        const unsigned short* hrow = use_init ? hinit_b : (hprev + (size_t)ai * DD);
        #pragma unroll
        for (int i = 0; i < 2; ++i) {
            const int cc = p2 * 2 + i;            // 16B chunk of the 128-wide h row
            const int kk = gs * 4 + (cc >> 2);
            const int qq = cc & 3;
            *(uint4*)&hs[kk * 1024 + qq * 256 + gr * 8] = *(const uint4*)(hrow + cc * 8);
        }
        const float* crow = use_init ? cinit_f : (cprev + (size_t)ai * DD);
        float* cdst = &cs[(gs * 32 + gr) * CSW];
        #pragma unroll
        for (int i = 0; i < 4; ++i) {
            const int cf = p2 * 4 + i;            // float4 chunk of the 128-wide c row
            *(float4*)(cdst + cf * 4) = *(const float4*)(crow + cf * 4);
        }
    }
    __syncthreads();

    // ---- MFMA: wave dt handles d-range [dt*16, +16), 2 m-tiles, 9 gates, K=256 ----
    const int lane = tid & 63;
    const int dt   = tid >> 6;            // 0..7
    const int m    = lane & 15;
    const int q    = lane >> 4;
    const int d    = dt * 16 + m;

    const unsigned short* wb = wpack + (size_t)dt * 4096 + (size_t)lane * 8;
    // fragment (g, kk) at wb + g*32768 + kk*512 (ushort units)

    f32x4 acc[9][2];
    #pragma unroll
    for (int g = 0; g < 9; ++g) { acc[g][0] = (f32x4)0.0f; acc[g][1] = (f32x4)0.0f; }

    #pragma unroll
    for (int kk = 0; kk < 8; ++kk) {
        const int xo = kk * 1024 + q * 256 + m * 8;
        bf16x8 a0 = *(const bf16x8*)&xs[xo];
        bf16x8 a1 = *(const bf16x8*)&xs[xo + 128];   // rows 16..31
        bf16x8 h0 = *(const bf16x8*)&hs[xo];
        bf16x8 h1 = *(const bf16x8*)&hs[xo + 128];
        #pragma unroll
        for (int g = 0; g < 4; ++g) {
            bf16x8 b = *(const bf16x8*)(wb + (size_t)g * 32768 + kk * 512);
            acc[g][0] = __builtin_amdgcn_mfma_f32_16x16x32_bf16(a0, b, acc[g][0], 0, 0, 0);
            acc[g][1] = __builtin_amdgcn_mfma_f32_16x16x32_bf16(a1, b, acc[g][1], 0, 0, 0);
        }
        #pragma unroll
        for (int g = 4; g < 9; ++g) {
            bf16x8 b = *(const bf16x8*)(wb + (size_t)g * 32768 + kk * 512);
            acc[g][0] = __builtin_amdgcn_mfma_f32_16x16x32_bf16(h0, b, acc[g][0], 0, 0, 0);
            acc[g][1] = __builtin_amdgcn_mfma_f32_16x16x32_bf16(h1, b, acc[g][1], 0, 0, 0);
        }
    }

    // ---- pointwise LSTM: acc[g][mt][j] -> node mt*16+q*4+j, dim d; c from LDS ----
    const float bfv = bias[d], biv = bias[128 + d], buv = bias[256 + d], bov = bias[384 + d];
    #pragma unroll
    for (int mt = 0; mt < 2; ++mt) {
        #pragma unroll
        for (int j = 0; j < 4; ++j) {
            const int rr = mt * 16 + q * 4 + j;
            const int nd = bm * BM + rr;
            const float ca = cs[rr * CSW + d];
            const float cb = cs[(32 + rr) * CSW + d];
            const float fx = acc[0][mt][j] + bfv;
            const float ix = acc[1][mt][j] + biv;
            const float ux = acc[2][mt][j] + buv;
            const float ox = acc[3][mt][j] + bov;
            const float f1 = sig_(fx + acc[4][mt][j]);
            const float f2 = sig_(fx + acc[5][mt][j]);
            const float ig = sig_(ix + acc[6][mt][j]);
            const float ug = tanh_(ux + acc[7][mt][j]);
            const float og = sig_(ox + acc[8][mt][j]);
            const float nc = ig * ug + f1 * ca + f2 * cb;
            const float nh = og * tanh_(nc);
            const size_t o = (size_t)nd * DD + d;
            hnew[o] = f2b(nh);
            outh[o] = nh;
            outc[o] = nc;
        }
    }
}

extern "C" void kernel_launch(void* const* d_in, const int* in_sizes, int n_in,
                              void* d_out, int out_size, void* d_ws, size_t ws_size,
                              hipStream_t stream) {
    const void* tensor  = d_in[0];
    const int*  indices = (const int*)d_in[1];
    const void* h_init  = d_in[2];
    const void* c_init  = d_in[3];
    const void* Ww      = d_in[4];
    const void* Wb      = d_in[5];
    const void* Uf1     = d_in[6];
    const void* Uf2     = d_in[7];
    const void* Uiuo    = d_in[8];
    float* out = (float*)d_out;   // fp32: [h(L,N,D) | c(L,N,D)]

    char* wsb = (char*)d_ws;
    int* flag                = (int*)wsb;                               // @0
    unsigned short* wpack    = (unsigned short*)(wsb + 256);            // 589,824 B
    float* bias              = (float*)(wsb + 590336);                  // 2 KB
    unsigned short* hinit_b  = (unsigned short*)(wsb + 592640);         // 256 B
    float* cinit_f           = (float*)(wsb + 593152);                  // 512 B
    unsigned short* hb0      = (unsigned short*)(wsb + (1u << 20));             // 2 MB
    unsigned short* hb1      = (unsigned short*)(wsb + (1u << 20) + 2097152);   // 2 MB

    detect_kernel<<<1, 64, 0, stream>>>((const unsigned short*)tensor, flag);
    convert_kernel<<<1155, 256, 0, stream>>>(Ww, Wb, Uf1, Uf2, Uiuo, h_init, c_init,
                                             wpack, bias, hinit_b, cinit_f, flag);

    unsigned short* hp = hb0;
    unsigned short* hn = hb1;
    for (int l = 0; l < LVL; ++l) {
        const float* cprev = (l == 0) ? (const float*)out
                                      : (const float*)(out + (size_t)(LVL + l - 1) * NN * DD);
        level_kernel<<<NN / BM, 512, 0, stream>>>(
            tensor, l,
            indices + (size_t)l * NN * 2,
            hp, cprev, hn,
            out + (size_t)l * NN * DD,
            out + (size_t)(LVL + l) * NN * DD,
            wpack, bias, hinit_b, cinit_f, flag, (l == 0) ? 1 : 0);
        unsigned short* th = hp; hp = hn; hn = th;
    }
}

// Round 6
// 767.407 us; speedup vs baseline: 1.1605x; 1.1605x over previous
//
#include <hip/hip_runtime.h>
#include <stdint.h>

#define LVL 24
#define NN  8192
#define DIN 256
#define DD  128
#define BM  32
#define NT  (NN / BM)   // 256 node-tiles per level == persistent grid size
#define CSW 132         // fused cs row stride (floats)

typedef __attribute__((ext_vector_type(8))) short bf16x8;
typedef __attribute__((ext_vector_type(4))) float f32x4;

__device__ __forceinline__ float b2f(unsigned short u) {
    union { unsigned int i; float f; } v; v.i = ((unsigned int)u) << 16; return v.f;
}
__device__ __forceinline__ unsigned short f2b(float f) {
    union { float f; unsigned int i; } v; v.f = f;
    unsigned int x = v.i;
    return (unsigned short)((x + 0x7fffu + ((x >> 16) & 1u)) >> 16);  // RNE
}
__device__ __forceinline__ float sig_(float x) { return 1.0f / (1.0f + __expf(-x)); }
__device__ __forceinline__ float tanh_(float x) {
    float e = __expf(2.0f * x);
    return (e - 1.0f) / (e + 1.0f);
}
__device__ __forceinline__ float ldf(const void* p, size_t i, int isf) {
    return isf ? ((const float*)p)[i] : b2f(((const unsigned short*)p)[i]);
}
// agent-scope (cross-XCD visible) scalar store: bypasses the non-coherent local L2
__device__ __forceinline__ void st_agent(float* p, float v) {
    __hip_atomic_store(p, v, __ATOMIC_RELAXED, __HIP_MEMORY_SCOPE_AGENT);
}

// ---------------- dtype detector (unchanged) ----------------
__global__ void detect_kernel(const unsigned short* __restrict__ t, int* __restrict__ flag) {
    __shared__ int cnt;
    if (threadIdx.x == 0) cnt = 0;
    __syncthreads();
    int bad = 0;
    #pragma unroll
    for (int r = 0; r < 4; ++r) {
        unsigned short u = t[(threadIdx.x * 4 + r) * 2];
        int e = (u >> 7) & 255;
        bad += (e >= 136 || (e >= 1 && e <= 90)) ? 1 : 0;
    }
    atomicAdd(&cnt, bad);
    __syncthreads();
    if (threadIdx.x == 0) *flag = (cnt > 16) ? 1 : 0;
}

// ---------------- weight conversion into FRAGMENT-MAJOR packed layout ----------------
// Logical rows: [0,512)=W_w(f,i,u,o); [512,640)=U_f1; [640,768)=U_f2; [768,1152)=U_iuo.
// Packed element index: ((g*8+dt)*8 + kk)*512 + (q*16+m)*8 + j
//   where row = g*128 + dt*16 + m, col = kk*32 + q*8 + j.
// bid==1155 zeroes the per-(level,tile) ready flags (required before each fused run).
__global__ __launch_bounds__(256)
void convert_kernel(const void* Ww, const void* Wb, const void* Uf1, const void* Uf2,
                    const void* Uiuo, const void* hini, const void* cini,
                    unsigned short* __restrict__ wpack, float* __restrict__ bias,
                    unsigned short* __restrict__ hinit_b, float* __restrict__ cinit_f,
                    unsigned int* __restrict__ rdy,
                    const int* __restrict__ flag) {
    const int isf = *flag;
    const int bid = blockIdx.x;
    const int t = threadIdx.x;
    if (bid < 1152) {
        const int row = bid, col = t;
        float v;
        if (row < 512)       v = ldf(Ww,   (size_t)row * DIN + col, isf);
        else if (row < 640)  v = ldf(Uf1,  (size_t)(row - 512) * DIN + col, isf);
        else if (row < 768)  v = ldf(Uf2,  (size_t)(row - 640) * DIN + col, isf);
        else                 v = ldf(Uiuo, (size_t)(row - 768) * DIN + col, isf);
        const int g  = row >> 7;
        const int wr = row & 127;
        const int dt = wr >> 4;
        const int mm = wr & 15;
        const int kk = col >> 5;
        const int q  = (col >> 3) & 3;
        const int j  = col & 7;
        const size_t pos = (size_t)((g * 8 + dt) * 8 + kk) * 512 + (q * 16 + mm) * 8 + j;
        wpack[pos] = f2b(v);
    } else if (bid == 1152) {
        bias[t] = ldf(Wb, t, isf);
    } else if (bid == 1153) {
        bias[256 + t] = ldf(Wb, 256 + t, isf);
    } else if (bid == 1154) {
        if (t < 128) hinit_b[t] = f2b(ldf(hini, t, isf));
        else if (t < 256) cinit_f[t - 128] = ldf(cini, t - 128, isf);
    } else {
        for (int i = t; i < LVL * NT; i += 256) rdy[i] = 0u;
    }
}

// ---- x tile staging for 512-thread blocks (fragment-linear LDS layout) ----
__device__ __forceinline__ void stage_x512(unsigned short* __restrict__ xsbuf,
                                           const void* __restrict__ xbase,
                                           int level, int tile, int tid, int isf) {
    const int r  = tid & 31;
    const int u0 = tid >> 5;          // 0..15
    #pragma unroll
    for (int du = 0; du < 2; ++du) {
        const int u = u0 + du * 16;   // octet of the 256-wide row
        const int kk = u >> 2, qq = u & 3;
        const size_t re = (size_t)level * NN * DIN + (size_t)(tile * BM + r) * DIN + u * 8;
        union { unsigned short us[8]; uint4 v; } t;
        if (isf) {
            const float4* xr = (const float4*)((const float*)xbase + re);
            float4 v0 = xr[0], v1 = xr[1];
            t.us[0] = f2b(v0.x); t.us[1] = f2b(v0.y); t.us[2] = f2b(v0.z); t.us[3] = f2b(v0.w);
            t.us[4] = f2b(v1.x); t.us[5] = f2b(v1.y); t.us[6] = f2b(v1.z); t.us[7] = f2b(v1.w);
        } else {
            t.v = *(const uint4*)((const unsigned short*)xbase + re);
        }
        *(uint4*)&xsbuf[kk * 1024 + qq * 256 + r * 8] = t.v;
    }
}

// ---------------- persistent dataflow kernel: no barriers, no launches ----------------
// Block b owns node-tile b (32 nodes x full 128 d) at EVERY level. Cross-level dependency
// via per-(level,tile) flags: writer publishes after __syncthreads (drains vmcnt) with an
// agent-scope store; readers poll only their 2 children's tiles. State = the out slabs
// (write-once -> cached reads safe; writes agent-scope so they reach the coherent point).
__global__ __launch_bounds__(512, 2)
void fused_kernel(const void* __restrict__ xbase,
                  const int* __restrict__ idxall,        // [L, NN, 2]
                  float* __restrict__ out,               // [2L, NN, DD] (h slabs | c slabs)
                  const unsigned short* __restrict__ wpack,
                  const float* __restrict__ bias,
                  const unsigned short* __restrict__ hinit_b,
                  const float* __restrict__ cinit_f,
                  const int* __restrict__ flag,
                  unsigned int* __restrict__ rdy) {
    __shared__ unsigned short xs[2][8192];   // 32 KB double-buffered x tile
    __shared__ unsigned short hs[8192];      // 16 KB child-h concat (bf16)
    __shared__ float cs[64 * CSW];           // 33.8 KB child-c

    const int tid  = threadIdx.x;
    const int isf  = *flag;
    const int tile = blockIdx.x;             // 0..255

    // gather roles
    const int gr = tid & 31;                 // node row in tile
    const int gs = (tid >> 5) & 1;           // child 0/1
    const int p2 = tid >> 6;                 // 16-float chunk of the 128-wide child row

    // MFMA roles
    const int lane = tid & 63;
    const int dt   = tid >> 6;               // 0..7 (wave = 16-d slice)
    const int m    = lane & 15;
    const int q    = lane >> 4;
    const int d    = dt * 16 + m;
    const unsigned short* wb = wpack + (size_t)dt * 4096 + (size_t)lane * 8;
    const float bfv = bias[d], biv = bias[128 + d], buv = bias[256 + d], bov = bias[384 + d];

    stage_x512(xs[0], xbase, 0, tile, tid, isf);
    int ai = idxall[(size_t)(tile * BM + gr) * 2 + gs];   // level-0 idx (unused: all init)

    for (int l = 0; l < LVL; ++l) {
        const int use_init = (l == 0) || (ai < 0);

        // ---- wait for children tiles (dataflow, per-lane) ----
        if (l > 0 && ai >= 0) {
            const unsigned int* fp = &rdy[(size_t)(l - 1) * NT + (ai >> 5)];
            while (__hip_atomic_load(fp, __ATOMIC_RELAXED, __HIP_MEMORY_SCOPE_AGENT) == 0u)
                __builtin_amdgcn_s_sleep(1);
        }
        asm volatile("" ::: "memory");

        // ---- issue h/c gather loads (cached; lines are write-once, touched post-flag) ----
        float4 hv0, hv1, hv2, hv3, cv0, cv1, cv2, cv3;
        if (use_init) {
            const unsigned short* hi = hinit_b + p2 * 16;
            hv0 = make_float4(b2f(hi[0]), b2f(hi[1]), b2f(hi[2]), b2f(hi[3]));
            hv1 = make_float4(b2f(hi[4]), b2f(hi[5]), b2f(hi[6]), b2f(hi[7]));
            hv2 = make_float4(b2f(hi[8]), b2f(hi[9]), b2f(hi[10]), b2f(hi[11]));
            hv3 = make_float4(b2f(hi[12]), b2f(hi[13]), b2f(hi[14]), b2f(hi[15]));
            const float4* ci = (const float4*)(cinit_f + p2 * 16);
            cv0 = ci[0]; cv1 = ci[1]; cv2 = ci[2]; cv3 = ci[3];
        } else {
            const float4* hrow = (const float4*)(out + (size_t)(l - 1) * NN * DD
                                                 + (size_t)ai * DD + p2 * 16);
            hv0 = hrow[0]; hv1 = hrow[1]; hv2 = hrow[2]; hv3 = hrow[3];
            const float4* crow = (const float4*)(out + (size_t)(LVL + l - 1) * NN * DD
                                                 + (size_t)ai * DD + p2 * 16);
            cv0 = crow[0]; cv1 = crow[1]; cv2 = crow[2]; cv3 = crow[3];
        }

        // ---- x-gate MFMAs while gather loads are in flight (need xs only) ----
        const unsigned short* __restrict__ xcur = xs[l & 1];
        f32x4 acc[9][2];
        #pragma unroll
        for (int g = 0; g < 9; ++g) { acc[g][0] = (f32x4)0.0f; acc[g][1] = (f32x4)0.0f; }
        #pragma unroll
        for (int kk = 0; kk < 8; ++kk) {
            const int xo = kk * 1024 + q * 256 + m * 8;
            bf16x8 a0 = *(const bf16x8*)&xcur[xo];
            bf16x8 a1 = *(const bf16x8*)&xcur[xo + 128];
            #pragma unroll
            for (int g = 0; g < 4; ++g) {
                bf16x8 b = *(const bf16x8*)(wb + (size_t)g * 32768 + kk * 512);
                acc[g][0] = __builtin_amdgcn_mfma_f32_16x16x32_bf16(a0, b, acc[g][0], 0, 0, 0);
                acc[g][1] = __builtin_amdgcn_mfma_f32_16x16x32_bf16(a1, b, acc[g][1], 0, 0, 0);
            }
        }

        // ---- land gathered h (as bf16) and c into LDS ----
        {
            unsigned int w0 = (unsigned int)f2b(hv0.x) | ((unsigned int)f2b(hv0.y) << 16);
            unsigned int w1 = (unsigned int)f2b(hv0.z) | ((unsigned int)f2b(hv0.w) << 16);
            unsigned int w2 = (unsigned int)f2b(hv1.x) | ((unsigned int)f2b(hv1.y) << 16);
            unsigned int w3 = (unsigned int)f2b(hv1.z) | ((unsigned int)f2b(hv1.w) << 16);
            unsigned int w4 = (unsigned int)f2b(hv2.x) | ((unsigned int)f2b(hv2.y) << 16);
            unsigned int w5 = (unsigned int)f2b(hv2.z) | ((unsigned int)f2b(hv2.w) << 16);
            unsigned int w6 = (unsigned int)f2b(hv3.x) | ((unsigned int)f2b(hv3.y) << 16);
            unsigned int w7 = (unsigned int)f2b(hv3.z) | ((unsigned int)f2b(hv3.w) << 16);
            const int u0 = gs * 16 + p2 * 2;
            const int u1 = u0 + 1;
            *(uint4*)&hs[(u0 >> 2) * 1024 + (u0 & 3) * 256 + gr * 8] =
                make_uint4(w0, w1, w2, w3);
            *(uint4*)&hs[(u1 >> 2) * 1024 + (u1 & 3) * 256 + gr * 8] =
                make_uint4(w4, w5, w6, w7);
            float4* cd = (float4*)&cs[(gs * 32 + gr) * CSW + p2 * 16];
            cd[0] = cv0; cd[1] = cv1; cd[2] = cv2; cd[3] = cv3;
        }
        __syncthreads();

        // ---- h-gate MFMAs ----
        #pragma unroll
        for (int kk = 0; kk < 8; ++kk) {
            const int xo = kk * 1024 + q * 256 + m * 8;
            bf16x8 h0 = *(const bf16x8*)&hs[xo];
            bf16x8 h1 = *(const bf16x8*)&hs[xo + 128];
            #pragma unroll
            for (int g = 4; g < 9; ++g) {
                bf16x8 b = *(const bf16x8*)(wb + (size_t)g * 32768 + kk * 512);
                acc[g][0] = __builtin_amdgcn_mfma_f32_16x16x32_bf16(h0, b, acc[g][0], 0, 0, 0);
                acc[g][1] = __builtin_amdgcn_mfma_f32_16x16x32_bf16(h1, b, acc[g][1], 0, 0, 0);
            }
        }

        // ---- prefetch next level's x and idx ----
        if (l + 1 < LVL) {
            stage_x512(xs[(l + 1) & 1], xbase, l + 1, tile, tid, isf);
            ai = idxall[(size_t)(l + 1) * NN * 2 + (size_t)(tile * BM + gr) * 2 + gs];
        }

        // ---- pointwise LSTM; outputs published agent-scope (they are next level's state) ----
        float* __restrict__ outh = out + (size_t)l * NN * DD;
        float* __restrict__ outc = out + (size_t)(LVL + l) * NN * DD;
        #pragma unroll
        for (int mt = 0; mt < 2; ++mt) {
            #pragma unroll
            for (int j = 0; j < 4; ++j) {
                const int rr = mt * 16 + q * 4 + j;
                const int nd = tile * BM + rr;
                const float ca = cs[rr * CSW + d];
                const float cb = cs[(32 + rr) * CSW + d];
                const float fx = acc[0][mt][j] + bfv;
                const float ix = acc[1][mt][j] + biv;
                const float ux = acc[2][mt][j] + buv;
                const float ox = acc[3][mt][j] + bov;
                const float f1 = sig_(fx + acc[4][mt][j]);
                const float f2 = sig_(fx + acc[5][mt][j]);
                const float ig = sig_(ix + acc[6][mt][j]);
                const float ug = tanh_(ux + acc[7][mt][j]);
                const float og = sig_(ox + acc[8][mt][j]);
                const float nc = ig * ug + f1 * ca + f2 * cb;
                const float nh = og * tanh_(nc);
                const size_t o = (size_t)nd * DD + d;
                st_agent(&outh[o], nh);
                st_agent(&outc[o], nc);
            }
        }

        // ---- publish: __syncthreads drains all threads' stores (vmcnt(0) before s_barrier) ----
        __syncthreads();
        if (tid == 0)
            __hip_atomic_store(&rdy[(size_t)l * NT + tile], 1u,
                               __ATOMIC_RELAXED, __HIP_MEMORY_SCOPE_AGENT);
    }
}

// ---------------- fallback: per-level kernel (round-3 structure, 748 us proven) ----------------
__global__ __launch_bounds__(256, 3)
void level_kernel(const void* __restrict__ xbase, int level,
                  const int* __restrict__ idx,
                  const unsigned short* __restrict__ hprev,
                  const float* __restrict__ cprev,
                  unsigned short* __restrict__ hnew,
                  float* __restrict__ outh,
                  float* __restrict__ outc,
                  const unsigned short* __restrict__ wpack,
                  const float* __restrict__ bias,
                  const unsigned short* __restrict__ hinit_b,
                  const float* __restrict__ cinit_f,
                  const int* __restrict__ flag,
                  int first) {
    __shared__ unsigned short xsl[8192];
    __shared__ unsigned short hsl[8192];
    __shared__ float csl[64 * 66];

    const int tid = threadIdx.x;
    const int isf = *flag;
    const int bm  = blockIdx.x;
    const int yh  = blockIdx.y;

    {
        const int u0 = tid >> 4;
        const int r0 = tid & 15;
        #pragma unroll
        for (int du = 0; du < 2; ++du) {
            const int u = u0 + du * 16;
            const int kk = u >> 2, qq = u & 3;
            #pragma unroll
            for (int dr = 0; dr < 2; ++dr) {
                const int r = r0 + dr * 16;
                const size_t re = (size_t)level * NN * DIN + (size_t)(bm * BM + r) * DIN + u * 8;
                union { unsigned short us[8]; uint4 v; } t;
                if (isf) {
                    const float4* xr = (const float4*)((const float*)xbase + re);
                    float4 v0 = xr[0], v1 = xr[1];
                    t.us[0] = f2b(v0.x); t.us[1] = f2b(v0.y); t.us[2] = f2b(v0.z); t.us[3] = f2b(v0.w);
                    t.us[4] = f2b(v1.x); t.us[5] = f2b(v1.y); t.us[6] = f2b(v1.z); t.us[7] = f2b(v1.w);
                } else {
                    t.v = *(const uint4*)((const unsigned short*)xbase + re);
                }
                *(uint4*)&xsl[kk * 1024 + qq * 256 + r * 8] = t.v;
            }
        }
    }
    {
        const int r  = tid & 31;
        const int sp = tid >> 5;
        const int s    = sp >> 2;
        const int part = sp & 3;
        const int ai = idx[(bm * BM + r) * 2 + s];
        const int use_init = (first || ai < 0);

        const unsigned short* hsrc = use_init ? (hinit_b + part * 32)
                                              : (hprev + (size_t)ai * DD + part * 32);
        const int kk = s * 4 + part;
        #pragma unroll
        for (int qq = 0; qq < 4; ++qq)
            *(uint4*)&hsl[kk * 1024 + qq * 256 + r * 8] = ((const uint4*)hsrc)[qq];

        const float* csrc = use_init ? (cinit_f + yh * 64 + part * 16)
                                     : (cprev + (size_t)ai * DD + yh * 64 + part * 16);
        float* cdst = &csl[(s * 32 + r) * 66 + part * 16];
        #pragma unroll
        for (int qq = 0; qq < 4; ++qq)
            ((float4*)cdst)[qq] = ((const float4*)csrc)[qq];
    }
    __syncthreads();

    const int lane = tid & 63;
    const int wave = tid >> 6;
    const int m    = lane & 15;
    const int q    = lane >> 4;
    const int dt   = yh * 4 + wave;
    const int d    = yh * 64 + wave * 16 + m;
    const unsigned short* wb = wpack + (size_t)dt * 4096 + (size_t)lane * 8;

    f32x4 acc[9][2];
    #pragma unroll
    for (int g = 0; g < 9; ++g) { acc[g][0] = (f32x4)0.0f; acc[g][1] = (f32x4)0.0f; }

    #pragma unroll
    for (int kk = 0; kk < 8; ++kk) {
        const int xo = kk * 1024 + q * 256 + m * 8;
        bf16x8 a0 = *(const bf16x8*)&xsl[xo];
        bf16x8 a1 = *(const bf16x8*)&xsl[xo + 128];
        bf16x8 h0 = *(const bf16x8*)&hsl[xo];
        bf16x8 h1 = *(const bf16x8*)&hsl[xo + 128];
        #pragma unroll
        for (int g = 0; g < 4; ++g) {
            bf16x8 b = *(const bf16x8*)(wb + (size_t)g * 32768 + kk * 512);
            acc[g][0] = __builtin_amdgcn_mfma_f32_16x16x32_bf16(a0, b, acc[g][0], 0, 0, 0);
            acc[g][1] = __builtin_amdgcn_mfma_f32_16x16x32_bf16(a1, b, acc[g][1], 0, 0, 0);
        }
        #pragma unroll
        for (int g = 4; g < 9; ++g) {
            bf16x8 b = *(const bf16x8*)(wb + (size_t)g * 32768 + kk * 512);
            acc[g][0] = __builtin_amdgcn_mfma_f32_16x16x32_bf16(h0, b, acc[g][0], 0, 0, 0);
            acc[g][1] = __builtin_amdgcn_mfma_f32_16x16x32_bf16(h1, b, acc[g][1], 0, 0, 0);
        }
    }

    const float bfv = bias[d], biv = bias[128 + d], buv = bias[256 + d], bov = bias[384 + d];
    const int dloc = wave * 16 + m;
    #pragma unroll
    for (int mt = 0; mt < 2; ++mt) {
        #pragma unroll
        for (int j = 0; j < 4; ++j) {
            const int rr = mt * 16 + q * 4 + j;
            const int nd = bm * BM + rr;
            const float ca = csl[rr * 66 + dloc];
            const float cb = csl[(32 + rr) * 66 + dloc];
            const float fx = acc[0][mt][j] + bfv;
            const float ix = acc[1][mt][j] + biv;
            const float ux = acc[2][mt][j] + buv;
            const float ox = acc[3][mt][j] + bov;
            const float f1 = sig_(fx + acc[4][mt][j]);
            const float f2 = sig_(fx + acc[5][mt][j]);
            const float ig = sig_(ix + acc[6][mt][j]);
            const float ug = tanh_(ux + acc[7][mt][j]);
            const float og = sig_(ox + acc[8][mt][j]);
            const float nc = ig * ug + f1 * ca + f2 * cb;
            const float nh = og * tanh_(nc);
            const size_t o = (size_t)nd * DD + d;
            hnew[o] = f2b(nh);
            outh[o] = nh;
            outc[o] = nc;
        }
    }
}

extern "C" void kernel_launch(void* const* d_in, const int* in_sizes, int n_in,
                              void* d_out, int out_size, void* d_ws, size_t ws_size,
                              hipStream_t stream) {
    const void* tensor  = d_in[0];
    const int*  indices = (const int*)d_in[1];
    const void* h_init  = d_in[2];
    const void* c_init  = d_in[3];
    const void* Ww      = d_in[4];
    const void* Wb      = d_in[5];
    const void* Uf1     = d_in[6];
    const void* Uf2     = d_in[7];
    const void* Uiuo    = d_in[8];
    float* out = (float*)d_out;   // fp32: [h(L,N,D) | c(L,N,D)]

    char* wsb = (char*)d_ws;
    int* flag                = (int*)wsb;                               // @0
    unsigned short* wpack    = (unsigned short*)(wsb + 256);            // 589,824 B
    float* bias              = (float*)(wsb + 590336);                  // 2 KB
    unsigned short* hinit_b  = (unsigned short*)(wsb + 592640);         // 256 B
    float* cinit_f           = (float*)(wsb + 593152);                  // 512 B
    unsigned int* rdy        = (unsigned int*)(wsb + 593920);           // 24,576 B flags
    unsigned short* hb0      = (unsigned short*)(wsb + (1u << 20));             // 2 MB (fallback)
    unsigned short* hb1      = (unsigned short*)(wsb + (1u << 20) + 2097152);   // 2 MB (fallback)

    detect_kernel<<<1, 64, 0, stream>>>((const unsigned short*)tensor, flag);
    convert_kernel<<<1156, 256, 0, stream>>>(Ww, Wb, Uf1, Uf2, Uiuo, h_init, c_init,
                                             wpack, bias, hinit_b, cinit_f, rdy, flag);

    static int nb = -1;
    if (nb < 0) {
        if (hipOccupancyMaxActiveBlocksPerMultiprocessor(&nb, fused_kernel, 512, 0)
            != hipSuccess) nb = 0;
    }

    if (nb >= 1) {
        // all 256 blocks co-resident (1/CU) -> dataflow flags cannot deadlock
        void* kargs[] = { (void*)&tensor, (void*)&indices, (void*)&out, (void*)&wpack,
                          (void*)&bias, (void*)&hinit_b, (void*)&cinit_f, (void*)&flag,
                          (void*)&rdy };
        hipLaunchCooperativeKernel((const void*)fused_kernel, dim3(NT), dim3(512),
                                   kargs, 0, stream);
    } else {
        unsigned short* hp = hb0;
        unsigned short* hn = hb1;
        for (int l = 0; l < LVL; ++l) {
            const float* cprev = (l == 0) ? (const float*)out
                                          : (const float*)(out + (size_t)(LVL + l - 1) * NN * DD);
            level_kernel<<<dim3(NN / BM, 2), 256, 0, stream>>>(
                tensor, l,
                indices + (size_t)l * NN * 2,
                hp, cprev, hn,
                out + (size_t)l * NN * DD,
                out + (size_t)(LVL + l) * NN * DD,
                wpack, bias, hinit_b, cinit_f, flag, (l == 0) ? 1 : 0);
            unsigned short* th = hp; hp = hn; hn = th;
        }
    }
}